// Round 1
// baseline (1669.715 us; speedup 1.0000x reference)
//
#include <hip/hip_runtime.h>

#define TPB 256
#define PIX_PER_BLK 64
#define N_CODES 1024
#define DIMS 256
#define CC_CODES 256   // codes per outer chunk
#define KD 32          // dims per inner chunk
#define PAD 36         // 36 floats = 144 B row stride (16B aligned, conflict-free inner reads)

// e2[c] = sum_d emb[c][d]^2
__global__ void e2_kernel(const float* __restrict__ emb, float* __restrict__ e2) {
    int c = blockIdx.x * blockDim.x + threadIdx.x;
    if (c < N_CODES) {
        const float4* row = (const float4*)(emb + (size_t)c * DIMS);
        float s = 0.f;
#pragma unroll
        for (int k = 0; k < DIMS / 4; ++k) {
            float4 v = row[k];
            s += v.x * v.x + v.y * v.y + v.z * v.z + v.w * v.w;
        }
        e2[c] = s;
    }
}

__global__ __launch_bounds__(TPB) void vq_kernel(const float* __restrict__ z,
                                                 const float* __restrict__ emb,
                                                 const float* __restrict__ e2g,
                                                 int* __restrict__ out) {
    // smem: xs[64][PAD] | es[256][PAD] | e2s[256]   = 47104 B -> 3 blocks/CU
    __shared__ __align__(16) float smem[64 * PAD + 256 * PAD + 256];
    float* xs  = smem;
    float* es  = smem + 64 * PAD;
    float* e2s = es + 256 * PAD;

    const int tid = threadIdx.x;
    const int pg  = tid & 15;   // pixel group: pixels pg + 16*j
    const int cg  = tid >> 4;   // code group:  codes  cg + 16*i (within chunk)
    const int pixbase = blockIdx.x * PIX_PER_BLK;   // 64-pixel blocks never cross t
    const int t  = pixbase >> 12;
    const int n0 = pixbase & 4095;

    const int lp = tid & 63;    // staging: pixel lane
    const int lr = tid >> 6;    // staging: dim row group (0..3)

    float bestd[4];
    int   besti[4];
#pragma unroll
    for (int j = 0; j < 4; ++j) { bestd[j] = 3.4e38f; besti[j] = 0; }

#pragma unroll 1
    for (int cc = 0; cc < N_CODES / CC_CODES; ++cc) {
        __syncthreads();                       // protect e2s/es reuse from prev iter
        e2s[tid] = e2g[cc * CC_CODES + tid];   // visible after first in-loop sync

        float acc[4][16];
#pragma unroll
        for (int j = 0; j < 4; ++j)
#pragma unroll
            for (int i = 0; i < 16; ++i) acc[j][i] = 0.f;

#pragma unroll 1
        for (int dcb = 0; dcb < DIMS / KD; ++dcb) {
            __syncthreads();   // prev compute finished before tiles overwritten
            // stage x tile: xs[p][d] = z[(t*256 + dcb*32 + d)*4096 + n0 + p]
            {
                const float* zp = z + ((size_t)(t * DIMS + dcb * KD + lr * 8) << 12) + n0 + lp;
#pragma unroll
                for (int k = 0; k < 8; ++k)
                    xs[lp * PAD + lr * 8 + k] = zp[(size_t)k << 12];
            }
            // stage e tile: es[cl][d] = emb[(cc*256+cl)*256 + dcb*32 + d], cl = tid
            {
                const float4* ep = (const float4*)(emb + (size_t)(cc * CC_CODES + tid) * DIMS + dcb * KD);
#pragma unroll
                for (int k = 0; k < 8; ++k)
                    *(float4*)&es[tid * PAD + k * 4] = ep[k];
            }
            __syncthreads();

            const float* xp  = xs + pg * PAD;
            const float* epp = es + cg * PAD;
#pragma unroll
            for (int d4 = 0; d4 < KD / 4; ++d4) {
                float4 a0 = *(const float4*)(xp + 0 * 16 * PAD + d4 * 4);
                float4 a1 = *(const float4*)(xp + 1 * 16 * PAD + d4 * 4);
                float4 a2 = *(const float4*)(xp + 2 * 16 * PAD + d4 * 4);
                float4 a3 = *(const float4*)(xp + 3 * 16 * PAD + d4 * 4);
#pragma unroll
                for (int i = 0; i < 16; ++i) {
                    float4 b = *(const float4*)(epp + i * 16 * PAD + d4 * 4);
                    acc[0][i] += a0.x * b.x + a0.y * b.y + a0.z * b.z + a0.w * b.w;
                    acc[1][i] += a1.x * b.x + a1.y * b.y + a1.z * b.z + a1.w * b.w;
                    acc[2][i] += a2.x * b.x + a2.y * b.y + a2.z * b.z + a2.w * b.w;
                    acc[3][i] += a3.x * b.x + a3.y * b.y + a3.z * b.z + a3.w * b.w;
                }
            }
        }

        // epilogue: dist = e2 - 2*dot  (||x||^2 dropped, argmin-invariant)
#pragma unroll
        for (int i = 0; i < 16; ++i) {
            float e2v = e2s[cg + 16 * i];
            int   c   = cc * CC_CODES + cg + 16 * i;   // monotonic per thread -> '<' keeps first
#pragma unroll
            for (int j = 0; j < 4; ++j) {
                float d = e2v - 2.f * acc[j][i];
                if (d < bestd[j]) { bestd[j] = d; besti[j] = c; }
            }
        }
    }

    // cross-thread argmin reduction over the 16 code groups (alias onto es)
    __syncthreads();
    float* redd = es;                  // [16][64]
    int*   redi = (int*)(es + 1024);   // [16][64]
#pragma unroll
    for (int j = 0; j < 4; ++j) {
        int p = pg + 16 * j;
        redd[cg * 64 + p] = bestd[j];
        redi[cg * 64 + p] = besti[j];
    }
    __syncthreads();
    if (tid < 64) {
        float bd = redd[tid];
        int   bi = redi[tid];
#pragma unroll
        for (int g = 1; g < 16; ++g) {
            float d  = redd[g * 64 + tid];
            int   i2 = redi[g * 64 + tid];
            if (d < bd || (d == bd && i2 < bi)) { bd = d; bi = i2; }
        }
        out[pixbase + tid] = bi;
    }
}

extern "C" void kernel_launch(void* const* d_in, const int* in_sizes, int n_in,
                              void* d_out, int out_size, void* d_ws, size_t ws_size,
                              hipStream_t stream) {
    const float* z   = (const float*)d_in[0];   // (16,256,64,64) fp32
    const float* emb = (const float*)d_in[1];   // (1024,256) fp32
    int*   out = (int*)d_out;                   // (16,64,64) int32
    float* e2  = (float*)d_ws;                  // 1024 floats scratch (re-poisoned -> recompute)

    e2_kernel<<<N_CODES / TPB, TPB, 0, stream>>>(emb, e2);
    vq_kernel<<<(16 * 64 * 64) / PIX_PER_BLK, TPB, 0, stream>>>(z, emb, e2, out);
}

// Round 2
// 602.825 us; speedup vs baseline: 2.7698x; 2.7698x over previous
//
#include <hip/hip_runtime.h>

#define TPB 256
#define PIX_PER_BLK 64
#define N_CODES 1024
#define DIMS 256
#define CC_CODES 256   // codes per outer chunk
#define KD 32          // dims per inner chunk
#define PAD 36         // 144 B row stride: rows hit distinct bank quads for stride-8/32 access

// e2[c] = sum_d emb[c][d]^2
__global__ void e2_kernel(const float* __restrict__ emb, float* __restrict__ e2) {
    int c = blockIdx.x * blockDim.x + threadIdx.x;
    if (c < N_CODES) {
        const float4* row = (const float4*)(emb + (size_t)c * DIMS);
        float s = 0.f;
#pragma unroll
        for (int k = 0; k < DIMS / 4; ++k) {
            float4 v = row[k];
            s += v.x * v.x + v.y * v.y + v.z * v.z + v.w * v.w;
        }
        e2[c] = s;
    }
}

__global__ __launch_bounds__(TPB, 2) void vq_kernel(const float* __restrict__ z,
                                                    const float* __restrict__ emb,
                                                    const float* __restrict__ e2g,
                                                    int* __restrict__ out) {
    // smem: xs[64][PAD] | es[256][PAD] | e2s[256]   = 47104 B
    __shared__ __align__(16) float smem[64 * PAD + 256 * PAD + 256];
    float* xs  = smem;
    float* es  = smem + 64 * PAD;
    float* e2s = es + 256 * PAD;

    const int tid = threadIdx.x;
    const int pg  = tid & 7;    // pixel group: pixels pg + 8*j   (8 lanes/wave share -> a broadcast)
    const int cg  = tid >> 3;   // code group 0..31: codes cg + 32*i (8 distinct rows/wave, distinct banks)
    const int pixbase = blockIdx.x * PIX_PER_BLK;
    const int t  = pixbase >> 12;
    const int n0 = pixbase & 4095;

    const int lp = tid & 63;    // staging: pixel lane
    const int lr = tid >> 6;    // staging: dim row group (0..3)

    float bestd[8];
    int   besti[8];
#pragma unroll
    for (int j = 0; j < 8; ++j) { bestd[j] = 3.4e38f; besti[j] = 0; }

#pragma unroll 1
    for (int cc = 0; cc < N_CODES / CC_CODES; ++cc) {
        __syncthreads();                       // protect e2s/es reuse from prev iter
        e2s[tid] = e2g[cc * CC_CODES + tid];   // visible after first in-loop sync

        float acc[8][8];
#pragma unroll
        for (int j = 0; j < 8; ++j)
#pragma unroll
            for (int i = 0; i < 8; ++i) acc[j][i] = 0.f;

#pragma unroll 1
        for (int dcb = 0; dcb < DIMS / KD; ++dcb) {
            __syncthreads();   // prev compute finished before tiles overwritten
            // stage x tile: xs[p][d] = z[(t*256 + dcb*32 + d)*4096 + n0 + p]
            {
                const float* zp = z + ((size_t)(t * DIMS + dcb * KD + lr * 8) << 12) + n0 + lp;
#pragma unroll
                for (int k = 0; k < 8; ++k)
                    xs[lp * PAD + lr * 8 + k] = zp[(size_t)k << 12];
            }
            // stage e tile: es[cl][d] = emb[(cc*256+cl)*256 + dcb*32 + d], cl = tid
            {
                const float4* ep = (const float4*)(emb + (size_t)(cc * CC_CODES + tid) * DIMS + dcb * KD);
#pragma unroll
                for (int k = 0; k < 8; ++k)
                    *(float4*)&es[tid * PAD + k * 4] = ep[k];
            }
            __syncthreads();

            // 8 px x 8 codes register tile; #pragma unroll 1 bounds live range:
            // peak live ~ 64 acc + 32 a + 4 b + addr -> no spill
#pragma unroll 1
            for (int d4 = 0; d4 < KD / 4; ++d4) {
                float4 a[8];
#pragma unroll
                for (int j = 0; j < 8; ++j)
                    a[j] = *(const float4*)(xs + (pg + 8 * j) * PAD + d4 * 4);
#pragma unroll
                for (int i = 0; i < 8; ++i) {
                    float4 b = *(const float4*)(es + (cg + 32 * i) * PAD + d4 * 4);
#pragma unroll
                    for (int j = 0; j < 8; ++j)
                        acc[j][i] += a[j].x * b.x + a[j].y * b.y + a[j].z * b.z + a[j].w * b.w;
                }
            }
        }

        // epilogue: dist = e2 - 2*dot  (||x||^2 dropped, argmin-invariant)
#pragma unroll
        for (int i = 0; i < 8; ++i) {
            float e2v = e2s[cg + 32 * i];
            int   c   = cc * CC_CODES + cg + 32 * i;   // strictly increasing per thread -> '<' keeps first
#pragma unroll
            for (int j = 0; j < 8; ++j) {
                float d = e2v - 2.f * acc[j][i];
                if (d < bestd[j]) { bestd[j] = d; besti[j] = c; }
            }
        }
    }

    // cross-thread argmin reduction: table [cg 0..31][px 0..63] aliased onto es
    __syncthreads();
    float* redd = es;                  // [32][64]
    int*   redi = (int*)(es + 2048);   // [32][64]
#pragma unroll
    for (int j = 0; j < 8; ++j) {
        int px = pg + 8 * j;
        redd[cg * 64 + px] = bestd[j];
        redi[cg * 64 + px] = besti[j];
    }
    __syncthreads();
    if (tid < 64) {
        float bd = redd[tid];
        int   bi = redi[tid];
#pragma unroll
        for (int g = 1; g < 32; ++g) {
            float d  = redd[g * 64 + tid];
            int   i2 = redi[g * 64 + tid];
            if (d < bd || (d == bd && i2 < bi)) { bd = d; bi = i2; }
        }
        out[pixbase + tid] = bi;
    }
}

extern "C" void kernel_launch(void* const* d_in, const int* in_sizes, int n_in,
                              void* d_out, int out_size, void* d_ws, size_t ws_size,
                              hipStream_t stream) {
    const float* z   = (const float*)d_in[0];   // (16,256,64,64) fp32
    const float* emb = (const float*)d_in[1];   // (1024,256) fp32
    int*   out = (int*)d_out;                   // (16,64,64) int32
    float* e2  = (float*)d_ws;                  // 1024 floats scratch (re-poisoned -> recompute)

    e2_kernel<<<N_CODES / TPB, TPB, 0, stream>>>(emb, e2);
    vq_kernel<<<(16 * 64 * 64) / PIX_PER_BLK, TPB, 0, stream>>>(z, emb, e2, out);
}

// Round 3
// 273.201 us; speedup vs baseline: 6.1117x; 2.2065x over previous
//
#include <hip/hip_runtime.h>
#include <hip/hip_bf16.h>

#define TPB 256
#define NCODES 1024
#define DIMS 256
#define PIXB 64
#define XPAD 264      // xs row stride (ushorts): 528 B, 16B-aligned, odd-ish bank pattern
#define EPAD 40       // es row stride (ushorts): 80 B, 16B-aligned
#define DELTA 3.0f    // screening margin (bf16 worst-case dot error ~1.3; 3.0 is safe)
#define CAP 16        // candidate capacity per pixel (overflow -> full rescan)

typedef __attribute__((ext_vector_type(8))) short bf16x8;
typedef __attribute__((ext_vector_type(4))) float f32x4;

// prep: eb[c][d] = bf16(emb[c][d]);  e2[c] = sum_d emb[c][d]^2 (exact fp32)
__global__ __launch_bounds__(64) void prep_kernel(const float* __restrict__ emb,
                                                  ushort* __restrict__ eb,
                                                  float* __restrict__ e2) {
    const int c = blockIdx.x;
    const int l = threadIdx.x;           // 64 lanes, 4 dims each
    float4 v = *(const float4*)(emb + (size_t)c * DIMS + 4 * l);
    __hip_bfloat16 h0 = __float2bfloat16(v.x), h1 = __float2bfloat16(v.y);
    __hip_bfloat16 h2 = __float2bfloat16(v.z), h3 = __float2bfloat16(v.w);
    ushort4 u;
    u.x = *(ushort*)&h0; u.y = *(ushort*)&h1; u.z = *(ushort*)&h2; u.w = *(ushort*)&h3;
    *(ushort4*)(eb + (size_t)c * DIMS + 4 * l) = u;
    float s = v.x * v.x + v.y * v.y + v.z * v.z + v.w * v.w;
#pragma unroll
    for (int off = 1; off < 64; off <<= 1) s += __shfl_xor(s, off);
    if (l == 0) e2[c] = s;
}

__global__ __launch_bounds__(TPB, 2) void vq_kernel(const float* __restrict__ z,
                                                    const float* __restrict__ emb,
                                                    const ushort* __restrict__ eb,
                                                    const float* __restrict__ e2g,
                                                    int* __restrict__ out) {
    __shared__ __align__(16) ushort xs[PIXB * XPAD];   // 33792 B: bf16 x, [px][dim]
    __shared__ __align__(16) ushort es[256 * EPAD];    // 20480 B: bf16 e tile, [code][32 dims]
    __shared__ float e2s[256];
    __shared__ float wmin[4 * 64];                     // per-wave chunk min per px
    __shared__ float minval[64];                       // global running min per px
    __shared__ int   cnt[64];
    __shared__ int   cand[64 * CAP];

    const int tid = threadIdx.x;
    const int w   = tid >> 6;     // wave 0..3
    const int L   = tid & 63;     // lane
    const int col = L & 15;       // MFMA col (= pixel within n-tile)
    const int q   = L >> 4;       // MFMA quad
    const int pixbase = blockIdx.x * PIXB;
    const int t  = pixbase >> 12;
    const int n0 = pixbase & 4095;

    // ---- phase 1: stage x (fp32 global -> bf16 LDS), wave w does dims w*64..+63 ----
    {
        const float* zp = z + (((size_t)t * DIMS + w * 64) << 12) + n0 + L;
#pragma unroll 8
        for (int i = 0; i < 64; ++i) {
            float v = zp[(size_t)i << 12];
            __hip_bfloat16 h = __float2bfloat16(v);
            xs[L * XPAD + w * 64 + i] = *(ushort*)&h;
        }
    }
    if (tid < 64) { minval[tid] = 3.4e38f; cnt[tid] = 0; }

    // ---- phase 2: MFMA screening over 4 chunks of 256 codes ----
    float bestAll = 0.f; (void)bestAll;
#pragma unroll 1
    for (int cc = 0; cc < 4; ++cc) {
        __syncthreads();                       // protect e2s / tables from prev iter readers
        e2s[tid] = e2g[cc * 256 + tid];

        f32x4 acc[4][4];
#pragma unroll
        for (int mt = 0; mt < 4; ++mt)
#pragma unroll
            for (int nt = 0; nt < 4; ++nt) acc[mt][nt] = (f32x4){0.f, 0.f, 0.f, 0.f};

#pragma unroll 1
        for (int kc = 0; kc < 8; ++kc) {
            __syncthreads();                   // prev compute done before es overwrite
            {   // stage es: thread t -> code row t, 32 dims of chunk kc
                const uint4* src = (const uint4*)(eb + (size_t)(cc * 256 + tid) * DIMS + kc * 32);
                uint4 r0 = src[0], r1 = src[1], r2 = src[2], r3 = src[3];
                uint4* dst = (uint4*)&es[tid * EPAD];
                dst[0] = r0; dst[1] = r1; dst[2] = r2; dst[3] = r3;
            }
            __syncthreads();

            bf16x8 af[4], bfr[4];
#pragma unroll
            for (int mt = 0; mt < 4; ++mt)
                af[mt] = *(const bf16x8*)&es[(w * 64 + mt * 16 + col) * EPAD + q * 8];
#pragma unroll
            for (int nt = 0; nt < 4; ++nt)
                bfr[nt] = *(const bf16x8*)&xs[(nt * 16 + col) * XPAD + kc * 32 + q * 8];
#pragma unroll
            for (int mt = 0; mt < 4; ++mt)
#pragma unroll
                for (int nt = 0; nt < 4; ++nt)
                    acc[mt][nt] = __builtin_amdgcn_mfma_f32_16x16x32_bf16(
                        af[mt], bfr[nt], acc[mt][nt], 0, 0, 0);
        }

        // epilogue: s = e2[c] - 2*dot ; C layout: col=lane&15 (px), row=q*4+r (code)
        // 1) per-(wave,px) chunk min
#pragma unroll
        for (int nt = 0; nt < 4; ++nt) {
            float m = 3.4e38f;
#pragma unroll
            for (int mt = 0; mt < 4; ++mt)
#pragma unroll
                for (int r = 0; r < 4; ++r) {
                    float s = e2s[w * 64 + mt * 16 + q * 4 + r] - 2.f * acc[mt][nt][r];
                    m = fminf(m, s);
                }
            m = fminf(m, __shfl_xor(m, 16));
            m = fminf(m, __shfl_xor(m, 32));
            wmin[w * 64 + nt * 16 + col] = m;    // all q-copies write same value
        }
        __syncthreads();
        if (tid < 64) {
            float m = minval[tid];
#pragma unroll
            for (int ww = 0; ww < 4; ++ww) m = fminf(m, wmin[ww * 64 + tid]);
            minval[tid] = m;
        }
        __syncthreads();
        // 2) candidate scan (running-min threshold => superset of final candidate set)
#pragma unroll
        for (int nt = 0; nt < 4; ++nt) {
            const int px = nt * 16 + col;
            const float thr = minval[px] + DELTA;
#pragma unroll
            for (int mt = 0; mt < 4; ++mt)
#pragma unroll
                for (int r = 0; r < 4; ++r) {
                    float s = e2s[w * 64 + mt * 16 + q * 4 + r] - 2.f * acc[mt][nt][r];
                    if (s <= thr) {
                        int pos = atomicAdd(&cnt[px], 1);
                        if (pos < CAP)
                            cand[px * CAP + pos] = cc * 256 + w * 64 + mt * 16 + q * 4 + r;
                    }
                }
        }
    }
    __syncthreads();

    // ---- phase 3: exact fp32 rescore of candidates; wave w does px w*16..+15 ----
#pragma unroll 1
    for (int pi = 0; pi < 16; ++pi) {
        const int px = w * 16 + pi;
        const int n  = cnt[px];
        // lane L holds dims 4L..4L+3 of x (exact fp32 from pristine z)
        const float* zp = z + (((size_t)t * DIMS + 4 * L) << 12) + n0 + px;
        float x0 = zp[0];
        float x1 = zp[(size_t)1 << 12];
        float x2 = zp[(size_t)2 << 12];
        float x3 = zp[(size_t)3 << 12];
        float bs = 3.4e38f;
        int   bi = 0;
        if (n <= CAP) {
            for (int k = 0; k < n; ++k) {
                int c = cand[px * CAP + k];
                float4 ev = *(const float4*)(emb + (size_t)c * DIMS + 4 * L);
                float p = x0 * ev.x + x1 * ev.y + x2 * ev.z + x3 * ev.w;
#pragma unroll
                for (int off = 1; off < 64; off <<= 1) p += __shfl_xor(p, off);
                float s = e2g[c] - 2.f * p;
                if (s < bs || (s == bs && c < bi)) { bs = s; bi = c; }
            }
        } else {
            // overflow fallback (expected never): exact scan of all codes
            for (int c = 0; c < NCODES; ++c) {
                float4 ev = *(const float4*)(emb + (size_t)c * DIMS + 4 * L);
                float p = x0 * ev.x + x1 * ev.y + x2 * ev.z + x3 * ev.w;
#pragma unroll
                for (int off = 1; off < 64; off <<= 1) p += __shfl_xor(p, off);
                float s = e2g[c] - 2.f * p;
                if (s < bs || (s == bs && c < bi)) { bs = s; bi = c; }
            }
        }
        if (L == 0) out[pixbase + px] = bi;
    }
}

extern "C" void kernel_launch(void* const* d_in, const int* in_sizes, int n_in,
                              void* d_out, int out_size, void* d_ws, size_t ws_size,
                              hipStream_t stream) {
    const float* z   = (const float*)d_in[0];   // (16,256,64,64) fp32
    const float* emb = (const float*)d_in[1];   // (1024,256) fp32
    int* out = (int*)d_out;                     // (16,64,64) int32

    ushort* eb = (ushort*)d_ws;                          // 1024*256 bf16 = 512 KB
    float*  e2 = (float*)((char*)d_ws + (size_t)NCODES * DIMS * sizeof(ushort)); // 4 KB

    prep_kernel<<<NCODES, 64, 0, stream>>>(emb, eb, e2);
    vq_kernel<<<(16 * 64 * 64) / PIXB, TPB, 0, stream>>>(z, emb, eb, e2, out);
}